// Round 1
// baseline (1330.663 us; speedup 1.0000x reference)
//
#include <hip/hip_runtime.h>
#include <hip/hip_bf16.h>
#include <stdint.h>

// Top-2 MoE router: s=8192 tokens, e=8 experts, capacity=2560.
// Output = cb_weight[s][8][cap] f32 ++ sec_mask[s][8][cap] (as float 0/1).
// Dominated by 1.34 GB of zero-fill writes -> memory-bound streaming store.

#define SCAN_THREADS 1024

// ---------------- Kernel 1: per-token softmax + top1/top2 ----------------
__global__ __launch_bounds__(256) void top2_kernel(
    const float* __restrict__ in,
    float* __restrict__ w1o, float* __restrict__ w2o,
    unsigned char* __restrict__ eo, int s) {
  int t = blockIdx.x * blockDim.x + threadIdx.x;
  if (t >= s) return;
  const float4* p = reinterpret_cast<const float4*>(in + (size_t)t * 8);
  float4 a = p[0], b = p[1];
  float v[8] = {a.x, a.y, a.z, a.w, b.x, b.y, b.z, b.w};
  float m = v[0];
#pragma unroll
  for (int i = 1; i < 8; ++i) m = fmaxf(m, v[i]);
  float ex[8];
  float sum = 0.f;
#pragma unroll
  for (int i = 0; i < 8; ++i) { ex[i] = expf(v[i] - m); sum += ex[i]; }
  float inv = 1.0f / sum;
  // argmax (first occurrence on ties -> strict >)
  int i1 = 0; float b1 = ex[0];
#pragma unroll
  for (int i = 1; i < 8; ++i) { if (ex[i] > b1) { b1 = ex[i]; i1 = i; } }
  int i2 = -1; float b2 = -1.f;
#pragma unroll
  for (int i = 0; i < 8; ++i) {
    if (i != i1 && ex[i] > b2) { b2 = ex[i]; i2 = i; }
  }
  w1o[t] = b1 * inv;
  w2o[t] = b2 * inv;
  eo[t] = (unsigned char)(i1 | (i2 << 3));
}

// ---------------- Kernel 2: token-order rank scan (single block) ----------------
__global__ __launch_bounds__(SCAN_THREADS) void scan_kernel(
    const unsigned char* __restrict__ eo,
    short* __restrict__ slots,  // [s][2], -1 = dropped
    int s, int cap) {
  __shared__ int wave_cnt[SCAN_THREADS / 64][8];
  __shared__ int base[8];
  __shared__ int tot1[8];
  const int tid = threadIdx.x;
  const int lane = tid & 63;
  const int wave = tid >> 6;
  const unsigned long long lt =
      (lane == 0) ? 0ULL : (~0ULL >> (64 - lane));
  const int rounds = (s + SCAN_THREADS - 1) / SCAN_THREADS;

  if (tid < 8) base[tid] = 0;
  __syncthreads();

  // pass 1: top-1 mask exclusive cumsum
  for (int k = 0; k < rounds; ++k) {
    const int t = k * SCAN_THREADS + tid;
    int my = -1;
    if (t < s) my = eo[t] & 7;
    int lanepre = 0;
#pragma unroll
    for (int e = 0; e < 8; ++e) {
      unsigned long long bal = __ballot(my == e);
      if (lane == 0) wave_cnt[wave][e] = __popcll(bal);
      if (my == e) lanepre = __popcll(bal & lt);
    }
    __syncthreads();
    if (my >= 0) {
      int wavepre = 0;
      for (int w = 0; w < wave; ++w) wavepre += wave_cnt[w][my];
      int rank = base[my] + wavepre + lanepre;
      slots[2 * t] = (rank < cap) ? (short)rank : (short)-1;
    }
    __syncthreads();
    if (tid < 8) {
      int add = 0;
      for (int w = 0; w < SCAN_THREADS / 64; ++w) add += wave_cnt[w][tid];
      base[tid] += add;
    }
    __syncthreads();
  }
  if (tid < 8) { tot1[tid] = base[tid]; base[tid] = 0; }
  __syncthreads();

  // pass 2: top-2 mask exclusive cumsum + total(top-1) offset
  for (int k = 0; k < rounds; ++k) {
    const int t = k * SCAN_THREADS + tid;
    int my = -1;
    if (t < s) my = (eo[t] >> 3) & 7;
    int lanepre = 0;
#pragma unroll
    for (int e = 0; e < 8; ++e) {
      unsigned long long bal = __ballot(my == e);
      if (lane == 0) wave_cnt[wave][e] = __popcll(bal);
      if (my == e) lanepre = __popcll(bal & lt);
    }
    __syncthreads();
    if (my >= 0) {
      int wavepre = 0;
      for (int w = 0; w < wave; ++w) wavepre += wave_cnt[w][my];
      int rank = base[my] + wavepre + lanepre + tot1[my];
      slots[2 * t + 1] = (rank < cap) ? (short)rank : (short)-1;
    }
    __syncthreads();
    if (tid < 8) {
      int add = 0;
      for (int w = 0; w < SCAN_THREADS / 64; ++w) add += wave_cnt[w][tid];
      base[tid] += add;
    }
    __syncthreads();
  }
}

// ---------------- Kernel 3: zero-fill + scatter (one block per token) ----------------
__global__ __launch_bounds__(256) void fill_scatter_kernel(
    const float* __restrict__ w1, const float* __restrict__ w2,
    const unsigned char* __restrict__ eo, const short* __restrict__ slots,
    float* __restrict__ out, int s, int cap) {
  const int t = blockIdx.x;
  const int row = 8 * cap;  // 20480 floats per token per plane
  float* cb = out + (size_t)t * row;
  float* mk = out + (size_t)s * row + (size_t)t * row;
  const float4 z = make_float4(0.f, 0.f, 0.f, 0.f);
  float4* cb4 = reinterpret_cast<float4*>(cb);
  float4* mk4 = reinterpret_cast<float4*>(mk);
  const int n4 = row / 4;  // 5120
  for (int i = threadIdx.x; i < n4; i += 256) {
    cb4[i] = z;
    mk4[i] = z;
  }
  __syncthreads();
  if (threadIdx.x < 2) {
    const unsigned char p = eo[t];
    const int e = (threadIdx.x == 0) ? (p & 7) : ((p >> 3) & 7);
    const short sl = slots[2 * t + threadIdx.x];
    const float v = (threadIdx.x == 0) ? w1[t] : w2[t];
    if (sl >= 0) {
      const int pos = e * cap + (int)sl;
      cb[pos] = v;
      mk[pos] = (v != 0.f) ? 1.f : 0.f;
    }
  }
}

extern "C" void kernel_launch(void* const* d_in, const int* in_sizes, int n_in,
                              void* d_out, int out_size, void* d_ws, size_t ws_size,
                              hipStream_t stream) {
  const float* in = (const float*)d_in[0];
  const int E = 8;
  const int s = in_sizes[0] / E;  // 8192
  // capacity = floor(2 * 1.25 * s / e), rounded up to even, min 4.
  int cap = (int)((5LL * s) / (2LL * E));
  cap += cap % 2;
  if (cap < 4) cap = 4;

  // workspace layout
  float* w1 = (float*)d_ws;                       // s f32
  float* w2 = w1 + s;                             // s f32
  unsigned char* eo = (unsigned char*)(w2 + s);   // s u8 (e1 | e2<<3)
  short* slots = (short*)((((uintptr_t)(eo + s)) + 15) & ~(uintptr_t)15);  // s*2 i16

  top2_kernel<<<(s + 255) / 256, 256, 0, stream>>>(in, w1, w2, eo, s);
  scan_kernel<<<1, SCAN_THREADS, 0, stream>>>(eo, slots, s, cap);
  fill_scatter_kernel<<<s, 256, 0, stream>>>(w1, w2, eo, slots, (float*)d_out, s, cap);
}